// Round 1
// baseline (76.400 us; speedup 1.0000x reference)
//
#include <hip/hip_runtime.h>

// FastGaussianModel: values[m] = sum_n exp(-0.5 * sum_d (p[m,d]-q[n,d])^2 * iv[n,d]) * w[n]
// Factored per gaussian into:  quad' = c' + a0*px+a1*py+a2*pz + b0*px^2+b1*py^2+b2*pz^2
// with the exp->exp2 conversion constant K = -0.5*log2(e) folded into all coeffs,
// so the inner loop is 6 FMA + v_exp_f32 + 1 FMA per (point,gaussian) pair.

constexpr int NG_CHUNK = 128;   // gaussians per block (chunk staged in LDS)
constexpr int BLOCK    = 256;   // one point per thread

// --- prep: per-gaussian coefficients, padded to chunk multiple (pad entries -> w=0) ---
__global__ void fgm_prep(const float* __restrict__ positions,
                         const float* __restrict__ log_scales,
                         const float* __restrict__ intensities,
                         float* __restrict__ coef, int N, int Npad) {
    int n = blockIdx.x * blockDim.x + threadIdx.x;
    if (n >= Npad) return;
    float4 c0 = make_float4(0.f, 0.f, 0.f, 0.f);
    float4 c1 = make_float4(0.f, 0.f, 0.f, 0.f);
    if (n < N) {
        const float K = -0.7213475204444817f;  // -0.5 * log2(e)
        float q0 = positions[3*n+0], q1 = positions[3*n+1], q2 = positions[3*n+2];
        float iv0 = 1.0f / (__expf(2.0f*log_scales[3*n+0]) + 1e-6f);
        float iv1 = 1.0f / (__expf(2.0f*log_scales[3*n+1]) + 1e-6f);
        float iv2 = 1.0f / (__expf(2.0f*log_scales[3*n+2]) + 1e-6f);
        float c = iv0*q0*q0 + iv1*q1*q1 + iv2*q2*q2;
        // layout: [a0,a1,a2,b0 | b1,b2,c,w]
        c0 = make_float4(K*(-2.f*iv0*q0), K*(-2.f*iv1*q1), K*(-2.f*iv2*q2), K*iv0);
        c1 = make_float4(K*iv1, K*iv2, K*c, intensities[n]);
    }
    float4* out = (float4*)coef;
    out[2*n+0] = c0;
    out[2*n+1] = c1;
}

// --- main: one point per thread, loop over a 128-gaussian LDS-staged chunk ---
__global__ __launch_bounds__(BLOCK) void fgm_main(const float* __restrict__ points,
                                                  const float* __restrict__ coef,
                                                  float* __restrict__ out, int M) {
    __shared__ float4 sc[NG_CHUNK * 2];  // 4 KB
    int base = blockIdx.y * NG_CHUNK;
    // stage: exactly 256 float4s
    const float4* gc = (const float4*)coef + base * 2;
    sc[threadIdx.x] = gc[threadIdx.x];
    __syncthreads();

    int m = blockIdx.x * blockDim.x + threadIdx.x;
    float px = 0.f, py = 0.f, pz = 0.f;
    if (m < M) {
        px = points[3*m+0];
        py = points[3*m+1];
        pz = points[3*m+2];
    }
    float px2 = px*px, py2 = py*py, pz2 = pz*pz;
    float acc = 0.f;
    #pragma unroll 4
    for (int n = 0; n < NG_CHUNK; ++n) {
        float4 c0 = sc[2*n+0];
        float4 c1 = sc[2*n+1];
        float t = __builtin_fmaf(c0.x, px,  c1.z);
        t = __builtin_fmaf(c0.y, py,  t);
        t = __builtin_fmaf(c0.z, pz,  t);
        t = __builtin_fmaf(c0.w, px2, t);
        t = __builtin_fmaf(c1.x, py2, t);
        t = __builtin_fmaf(c1.y, pz2, t);
        float g = __builtin_amdgcn_exp2f(t);   // v_exp_f32
        acc = __builtin_fmaf(g, c1.w, acc);
    }
    if (m < M) atomicAdd(&out[m], acc);
}

extern "C" void kernel_launch(void* const* d_in, const int* in_sizes, int n_in,
                              void* d_out, int out_size, void* d_ws, size_t ws_size,
                              hipStream_t stream) {
    const float* points      = (const float*)d_in[0];
    const float* positions   = (const float*)d_in[1];
    const float* log_scales  = (const float*)d_in[2];
    const float* intensities = (const float*)d_in[3];
    int M = in_sizes[0] / 3;
    int N = in_sizes[3];

    int chunks = (N + NG_CHUNK - 1) / NG_CHUNK;
    int Npad   = chunks * NG_CHUNK;

    float* coef = (float*)d_ws;  // Npad * 8 floats

    // output is accumulated via atomics -> zero it (d_out is poisoned 0xAA)
    hipMemsetAsync(d_out, 0, (size_t)out_size * sizeof(float), stream);

    fgm_prep<<<(Npad + 255) / 256, 256, 0, stream>>>(positions, log_scales,
                                                     intensities, coef, N, Npad);

    dim3 grid((M + BLOCK - 1) / BLOCK, chunks);
    fgm_main<<<grid, BLOCK, 0, stream>>>(points, coef, (float*)d_out, M);
}